// Round 1
// baseline (1250.799 us; speedup 1.0000x reference)
//
#include <hip/hip_runtime.h>

// ---------------------------------------------------------------------------
// Social model: agent LSTM (512x50, H=64), neighbour LSTM (16384x50, H=64),
// decoder LSTMCell (512, H=128, 30 steps) + linear head -> [512,30,2] fp32.
// Round 1: fp32 vector baseline. Encoder: 16 seq/block, 1 gate row per thread
// (weights in VGPRs), h/c/gates in LDS. Decoder: 2 seq/block, 512 thr.
// ---------------------------------------------------------------------------

__device__ __forceinline__ float sigf(float x) {
    return 1.0f / (1.0f + __expf(-x));
}
__device__ __forceinline__ float tanh_fast(float x) {
    x = fminf(fmaxf(x, -15.0f), 15.0f);
    float e = __expf(2.0f * x);
    return (e - 1.0f) / (e + 1.0f);
}

#define EM 16  // sequences per encoder block

// blocks 0..1023: neighbour sequences (16 each); blocks 1024..1055: agent.
__global__ __launch_bounds__(256) void enc_kernel(
    const float* __restrict__ ax, const float* __restrict__ nx,
    const float* __restrict__ a_wih, const float* __restrict__ a_whh,
    const float* __restrict__ a_bih, const float* __restrict__ a_bhh,
    const float* __restrict__ n_wih, const float* __restrict__ n_whh,
    const float* __restrict__ n_bih, const float* __restrict__ n_bhh,
    float* __restrict__ nh_out, float* __restrict__ ah_out)
{
    const int tid = threadIdx.x;
    const int blk = blockIdx.x;
    const bool agent = (blk >= 1024);
    const int seq0 = (agent ? (blk - 1024) : blk) * EM;
    const float* __restrict__ x   = agent ? ax : nx;
    const float* __restrict__ wih = agent ? a_wih : n_wih;
    const float* __restrict__ whh = agent ? a_whh : n_whh;
    const float* __restrict__ bih = agent ? a_bih : n_bih;
    const float* __restrict__ bhh = agent ? a_bhh : n_bhh;
    float* __restrict__ hout = agent ? ah_out : nh_out;

    __shared__ float xs[EM * 100];   // [s][t][xy]
    __shared__ float hs[EM][64];
    __shared__ float cs[EM][64];
    __shared__ float gs[EM][256];    // gate scratch, index = tid layout

    const int u  = tid >> 2;         // hidden unit 0..63
    const int tt = tid & 3;          // gate type: 0=i 1=f 2=g 3=o
    const int r  = tt * 64 + u;      // pytorch gate row

    float w[64];
    #pragma unroll
    for (int k = 0; k < 64; k += 4) {
        float4 t4 = *(const float4*)(whh + r * 64 + k);
        w[k] = t4.x; w[k+1] = t4.y; w[k+2] = t4.z; w[k+3] = t4.w;
    }
    const float wi0 = wih[r * 2], wi1 = wih[r * 2 + 1];
    const float bias = bih[r] + bhh[r];

    for (int i = tid; i < EM * 100; i += 256)
        xs[i] = x[(size_t)seq0 * 100 + i];
    for (int i = tid; i < EM * 64; i += 256) {
        (&hs[0][0])[i] = 0.0f;
        (&cs[0][0])[i] = 0.0f;
    }
    __syncthreads();

    for (int t = 0; t < 50; ++t) {
        // phase 1: gates = bias + Wih*x_t + Whh*h  (h broadcast from LDS)
        #pragma unroll 2
        for (int s = 0; s < EM; ++s) {
            const float4* hp = (const float4*)(&hs[s][0]);
            float a0 = 0.f, a1 = 0.f, a2 = 0.f, a3 = 0.f;
            #pragma unroll
            for (int k = 0; k < 16; ++k) {
                float4 h4 = hp[k];
                a0 = __builtin_fmaf(w[4*k+0], h4.x, a0);
                a1 = __builtin_fmaf(w[4*k+1], h4.y, a1);
                a2 = __builtin_fmaf(w[4*k+2], h4.z, a2);
                a3 = __builtin_fmaf(w[4*k+3], h4.w, a3);
            }
            float acc = bias + wi0 * xs[s*100 + 2*t] + wi1 * xs[s*100 + 2*t + 1]
                      + ((a0 + a1) + (a2 + a3));
            gs[s][tid] = acc;   // gs[s][4j+tt] = gate tt of unit j
        }
        __syncthreads();
        // phase 2: cell update; thread (j, slot) handles 4 sequences
        {
            const int j = tid & 63, slot = tid >> 6;
            #pragma unroll
            for (int si = 0; si < EM / 4; ++si) {
                const int s = slot + 4 * si;
                float4 g4 = *(const float4*)(&gs[s][4 * j]);  // (i,f,g,o)
                float ig = sigf(g4.x), fg = sigf(g4.y);
                float gg = tanh_fast(g4.z), og = sigf(g4.w);
                float c = fg * cs[s][j] + ig * gg;
                cs[s][j] = c;
                hs[s][j] = og * tanh_fast(c);
            }
        }
        __syncthreads();
    }

    for (int i = tid; i < EM * 64; i += 256)
        hout[(size_t)seq0 * 64 + i] = (&hs[0][0])[i];
}

// 256 blocks x 2 sequences. W = d_wih + d_whh pre-summed per thread.
__global__ __launch_bounds__(512) void dec_kernel(
    const float* __restrict__ ah, const float* __restrict__ nh,
    const float* __restrict__ d_wih, const float* __restrict__ d_whh,
    const float* __restrict__ d_bih, const float* __restrict__ d_bhh,
    const float* __restrict__ e_w, const float* __restrict__ e_b,
    float* __restrict__ out)
{
    const int tid = threadIdx.x;
    const int blk = blockIdx.x;

    const int u  = tid >> 2;          // 0..127
    const int tt = tid & 3;
    const int r  = tt * 128 + u;      // pytorch gate row in [0,512)

    float w[128];
    #pragma unroll
    for (int k = 0; k < 128; k += 4) {
        float4 aa = *(const float4*)(d_wih + r * 128 + k);
        float4 bb = *(const float4*)(d_whh + r * 128 + k);
        w[k]   = aa.x + bb.x;
        w[k+1] = aa.y + bb.y;
        w[k+2] = aa.z + bb.z;
        w[k+3] = aa.w + bb.w;
    }
    const float bias = d_bih[r] + d_bhh[r];

    __shared__ float hs[2][128];
    __shared__ float cs[2][128];
    __shared__ float gs[2][512];
    __shared__ float ews[2][128];
    __shared__ float ebs[2];

    if (tid < 256) {
        const int s = tid >> 7, j = tid & 127;
        const int gseq = blk * 2 + s;
        float v;
        if (j < 64) {
            v = ah[(size_t)gseq * 64 + j];
        } else {
            float acc = 0.0f;
            for (int n = 0; n < 32; ++n)
                acc += nh[(size_t)(gseq * 32 + n) * 64 + (j - 64)];
            v = acc * (1.0f / 32.0f);
        }
        hs[s][j] = v;
        cs[s][j] = 0.0f;
        ews[s][j] = e_w[tid];   // e_w flat [2][128]
    }
    if (tid < 2) ebs[tid] = e_b[tid];
    __syncthreads();

    for (int t = 0; t < 30; ++t) {
        #pragma unroll
        for (int s = 0; s < 2; ++s) {
            const float4* hp = (const float4*)(&hs[s][0]);
            float a0 = 0.f, a1 = 0.f, a2 = 0.f, a3 = 0.f;
            #pragma unroll
            for (int k = 0; k < 32; ++k) {
                float4 h4 = hp[k];
                a0 = __builtin_fmaf(w[4*k+0], h4.x, a0);
                a1 = __builtin_fmaf(w[4*k+1], h4.y, a1);
                a2 = __builtin_fmaf(w[4*k+2], h4.z, a2);
                a3 = __builtin_fmaf(w[4*k+3], h4.w, a3);
            }
            gs[s][tid] = bias + ((a0 + a1) + (a2 + a3));
        }
        __syncthreads();
        if (tid < 256) {
            const int s = tid >> 7, j = tid & 127;
            float4 g4 = *(const float4*)(&gs[s][4 * j]);  // (i,f,g,o)
            float ig = sigf(g4.x), fg = sigf(g4.y);
            float gg = tanh_fast(g4.z), og = sigf(g4.w);
            float c = fg * cs[s][j] + ig * gg;
            cs[s][j] = c;
            hs[s][j] = og * tanh_fast(c);
        }
        __syncthreads();
        // prediction head: wave wv handles (seq, out) pair
        {
            const int wv = tid >> 6, l = tid & 63;
            if (wv < 4) {
                const int s = wv >> 1, o = wv & 1;
                float p = hs[s][l] * ews[o][l] + hs[s][64 + l] * ews[o][64 + l];
                #pragma unroll
                for (int off = 32; off > 0; off >>= 1) p += __shfl_down(p, off);
                if (l == 0) out[((size_t)(blk * 2 + s) * 30 + t) * 2 + o] = p + ebs[o];
            }
        }
        // no extra barrier needed: pred reads hs only; hs next written after
        // the phase-1 barrier, which waves 0..3 reach only after pred.
    }
}

extern "C" void kernel_launch(void* const* d_in, const int* in_sizes, int n_in,
                              void* d_out, int out_size, void* d_ws, size_t ws_size,
                              hipStream_t stream)
{
    const float* agent_traj = (const float*)d_in[0];
    const float* neigh_traj = (const float*)d_in[1];
    const float* a_wih = (const float*)d_in[2];
    const float* a_whh = (const float*)d_in[3];
    const float* a_bih = (const float*)d_in[4];
    const float* a_bhh = (const float*)d_in[5];
    const float* n_wih = (const float*)d_in[6];
    const float* n_whh = (const float*)d_in[7];
    const float* n_bih = (const float*)d_in[8];
    const float* n_bhh = (const float*)d_in[9];
    const float* d_wih = (const float*)d_in[10];
    const float* d_whh = (const float*)d_in[11];
    const float* d_bih = (const float*)d_in[12];
    const float* d_bhh = (const float*)d_in[13];
    const float* e_w   = (const float*)d_in[14];
    const float* e_b   = (const float*)d_in[15];
    float* out = (float*)d_out;

    float* nh_ws = (float*)d_ws;            // 16384*64 fp32 = 4 MiB
    float* ah_ws = nh_ws + 16384 * 64;      // 512*64 fp32

    enc_kernel<<<dim3(1024 + 32), dim3(256), 0, stream>>>(
        agent_traj, neigh_traj,
        a_wih, a_whh, a_bih, a_bhh,
        n_wih, n_whh, n_bih, n_bhh,
        nh_ws, ah_ws);

    dec_kernel<<<dim3(256), dim3(512), 0, stream>>>(
        ah_ws, nh_ws, d_wih, d_whh, d_bih, d_bhh, e_w, e_b, out);
}

// Round 2
// 494.953 us; speedup vs baseline: 2.5271x; 2.5271x over previous
//
#include <hip/hip_runtime.h>

// ---------------------------------------------------------------------------
// R2: encoder rewritten on MFMA (16x16x32 bf16, split-precision 3-MFMA scheme
// for ~fp32 accuracy). 64 seqs/block, 256 threads; wave w owns unit-group w
// (units 16w..16w+15) for all 4 gates x all 64 seqs. Whh A-fragments live in
// VGPRs (hi+lo); h round-trips LDS (double-buffered, 288B padded rows).
// Decoder unchanged from R1 (validated).
// ---------------------------------------------------------------------------

typedef __attribute__((ext_vector_type(8))) short bf16x8;
typedef __attribute__((ext_vector_type(4))) float f32x4;
typedef unsigned int uint;

__device__ __forceinline__ float sigf(float x) {
    return 1.0f / (1.0f + __expf(-x));
}
__device__ __forceinline__ float tanh_fast(float x) {
    x = fminf(fmaxf(x, -15.0f), 15.0f);
    float e = __expf(2.0f * x);
    return (e - 1.0f) / (e + 1.0f);
}
__device__ __forceinline__ unsigned short bf_hi(float f) {
    union { float f; uint u; } v; v.f = f;
    return (unsigned short)(v.u >> 16);   // truncation; residual goes to lo
}
__device__ __forceinline__ float bf_f(unsigned short h) {
    union { float f; uint u; } v; v.u = ((uint)h) << 16;
    return v.f;
}

// grid: blocks 0..255 neighbour (64 seqs each), 256..263 agent (64 seqs each)
__global__ __launch_bounds__(256, 2) void enc2_kernel(
    const float* __restrict__ ax, const float* __restrict__ nx,
    const float* __restrict__ a_wih, const float* __restrict__ a_whh,
    const float* __restrict__ a_bih, const float* __restrict__ a_bhh,
    const float* __restrict__ n_wih, const float* __restrict__ n_whh,
    const float* __restrict__ n_bih, const float* __restrict__ n_bhh,
    float* __restrict__ nh_out, float* __restrict__ ah_out)
{
    const int tid = threadIdx.x, blk = blockIdx.x;
    const bool agent = (blk >= 256);
    const int seq0 = (agent ? (blk - 256) : blk) * 64;
    const float* __restrict__ x   = agent ? ax : nx;
    const float* __restrict__ wih = agent ? a_wih : n_wih;
    const float* __restrict__ whh = agent ? a_whh : n_whh;
    const float* __restrict__ bih = agent ? a_bih : n_bih;
    const float* __restrict__ bhh = agent ? a_bhh : n_bhh;
    float* __restrict__ hout = agent ? ah_out : nh_out;

    const int lane = tid & 63, wv = tid >> 6;
    const int col = lane & 15, quad = lane >> 4;

    // h buffers: [dbuf][seq][72 dwords]: bf16 hi units 0..63 at dwords 0..31,
    // bf16 lo at dwords 32..63, pad to 72 (288B row: 16B-aligned, banks spread)
    __shared__ __attribute__((aligned(16))) uint hb[2][64][72];
    __shared__ float xs[64 * 100];

    // ---- A fragments: Whh rows, split hi/lo bf16.
    // A-layout (16x16x32): row = tile_base + (lane&15), k = quad*8 + j.
    // M-tile for gate g, unit-group wv covers rows g*64 + 16*wv + 0..15.
    bf16x8 Ahi[4][2], Alo[4][2];
    #pragma unroll
    for (int g = 0; g < 4; ++g) {
        #pragma unroll
        for (int kt = 0; kt < 2; ++kt) {
            const float* p = whh + (size_t)(g * 64 + 16 * wv + col) * 64 + kt * 32 + quad * 8;
            float4 v0 = *(const float4*)p;
            float4 v1 = *(const float4*)(p + 4);
            float vv[8] = { v0.x, v0.y, v0.z, v0.w, v1.x, v1.y, v1.z, v1.w };
            bf16x8 h8, l8;
            #pragma unroll
            for (int j = 0; j < 8; ++j) {
                unsigned short hh = bf_hi(vv[j]);
                float r = vv[j] - bf_f(hh);
                h8[j] = (short)hh;
                l8[j] = (short)bf_hi(r);
            }
            Ahi[g][kt] = h8;
            Alo[g][kt] = l8;
        }
    }

    // ---- per-lane epilogue constants in C/D layout: row = g*64+16*wv+4*quad+r
    float bias[4][4], wi0[4][4], wi1[4][4];
    #pragma unroll
    for (int g = 0; g < 4; ++g) {
        #pragma unroll
        for (int r = 0; r < 4; ++r) {
            const int row = g * 64 + 16 * wv + 4 * quad + r;
            bias[g][r] = bih[row] + bhh[row];
            wi0[g][r] = wih[2 * row];
            wi1[g][r] = wih[2 * row + 1];
        }
    }

    // ---- stage x [64 seqs x 50 x 2] and zero h buffer 0
    {
        const float4* src = (const float4*)(x + (size_t)seq0 * 100);
        for (int i = tid; i < 64 * 25; i += 256) ((float4*)xs)[i] = src[i];
        for (int i = tid; i < 64 * 72; i += 256) (&hb[0][0][0])[i] = 0u;
    }
    __syncthreads();

    float c[4][4];
    #pragma unroll
    for (int nt = 0; nt < 4; ++nt)
        #pragma unroll
        for (int r = 0; r < 4; ++r) c[nt][r] = 0.0f;

    for (int t = 0; t < 50; ++t) {
        const int cur = t & 1, nxt = cur ^ 1;

        // init acc = bias + Wih * x_t   (fp32, per-lane)
        f32x4 acc[4][4];   // [gate][ntile]
        #pragma unroll
        for (int nt = 0; nt < 4; ++nt) {
            float2 xv = *(const float2*)&xs[(nt * 16 + col) * 100 + 2 * t];
            #pragma unroll
            for (int g = 0; g < 4; ++g) {
                f32x4 a;
                #pragma unroll
                for (int r = 0; r < 4; ++r)
                    a[r] = __builtin_fmaf(wi1[g][r], xv.y,
                           __builtin_fmaf(wi0[g][r], xv.x, bias[g][r]));
                acc[g][nt] = a;
            }
        }

        // accumulate Whh @ h: 3-MFMA split (hi*hi + hi*lo + lo*hi)
        #pragma unroll
        for (int nt = 0; nt < 4; ++nt) {
            const int sq = nt * 16 + col;
            #pragma unroll
            for (int kt = 0; kt < 2; ++kt) {
                bf16x8 Bhi = *(const bf16x8*)&hb[cur][sq][kt * 16 + quad * 4];
                bf16x8 Blo = *(const bf16x8*)&hb[cur][sq][32 + kt * 16 + quad * 4];
                #pragma unroll
                for (int g = 0; g < 4; ++g) {
                    acc[g][nt] = __builtin_amdgcn_mfma_f32_16x16x32_bf16(Ahi[g][kt], Bhi, acc[g][nt], 0, 0, 0);
                    acc[g][nt] = __builtin_amdgcn_mfma_f32_16x16x32_bf16(Ahi[g][kt], Blo, acc[g][nt], 0, 0, 0);
                    acc[g][nt] = __builtin_amdgcn_mfma_f32_16x16x32_bf16(Alo[g][kt], Bhi, acc[g][nt], 0, 0, 0);
                }
            }
        }

        // cell update (per lane: 4 seqs x 4 units) + h -> LDS (bf16 hi/lo)
        #pragma unroll
        for (int nt = 0; nt < 4; ++nt) {
            const int sq = nt * 16 + col;
            float hv[4];
            #pragma unroll
            for (int r = 0; r < 4; ++r) {
                float ig = sigf(acc[0][nt][r]);
                float fg = sigf(acc[1][nt][r]);
                float gg = tanh_fast(acc[2][nt][r]);
                float og = sigf(acc[3][nt][r]);
                float cc = __builtin_fmaf(fg, c[nt][r], ig * gg);
                c[nt][r] = cc;
                hv[r] = og * tanh_fast(cc);
            }
            unsigned short h0 = bf_hi(hv[0]), h1 = bf_hi(hv[1]);
            unsigned short h2 = bf_hi(hv[2]), h3 = bf_hi(hv[3]);
            uint2 hi2, lo2;
            hi2.x = (uint)h0 | ((uint)h1 << 16);
            hi2.y = (uint)h2 | ((uint)h3 << 16);
            lo2.x = (uint)bf_hi(hv[0] - bf_f(h0)) | ((uint)bf_hi(hv[1] - bf_f(h1)) << 16);
            lo2.y = (uint)bf_hi(hv[2] - bf_f(h2)) | ((uint)bf_hi(hv[3] - bf_f(h3)) << 16);
            const int di = 8 * wv + 2 * quad;   // dword index of unit 16*wv+4*quad
            *(uint2*)&hb[nxt][sq][di]      = hi2;
            *(uint2*)&hb[nxt][sq][32 + di] = lo2;
            if (t == 49) {
                #pragma unroll
                for (int r = 0; r < 4; ++r)
                    hout[(size_t)(seq0 + sq) * 64 + 16 * wv + 4 * quad + r] = hv[r];
            }
        }
        __syncthreads();
    }
}

// ---------------- decoder (unchanged from R1, validated) -------------------
__global__ __launch_bounds__(512) void dec_kernel(
    const float* __restrict__ ah, const float* __restrict__ nh,
    const float* __restrict__ d_wih, const float* __restrict__ d_whh,
    const float* __restrict__ d_bih, const float* __restrict__ d_bhh,
    const float* __restrict__ e_w, const float* __restrict__ e_b,
    float* __restrict__ out)
{
    const int tid = threadIdx.x;
    const int blk = blockIdx.x;

    const int u  = tid >> 2;
    const int tt = tid & 3;
    const int r  = tt * 128 + u;

    float w[128];
    #pragma unroll
    for (int k = 0; k < 128; k += 4) {
        float4 aa = *(const float4*)(d_wih + r * 128 + k);
        float4 bb = *(const float4*)(d_whh + r * 128 + k);
        w[k]   = aa.x + bb.x;
        w[k+1] = aa.y + bb.y;
        w[k+2] = aa.z + bb.z;
        w[k+3] = aa.w + bb.w;
    }
    const float bias = d_bih[r] + d_bhh[r];

    __shared__ float hs[2][128];
    __shared__ float cs[2][128];
    __shared__ float gs[2][512];
    __shared__ float ews[2][128];
    __shared__ float ebs[2];

    if (tid < 256) {
        const int s = tid >> 7, j = tid & 127;
        const int gseq = blk * 2 + s;
        float v;
        if (j < 64) {
            v = ah[(size_t)gseq * 64 + j];
        } else {
            float acc = 0.0f;
            for (int n = 0; n < 32; ++n)
                acc += nh[(size_t)(gseq * 32 + n) * 64 + (j - 64)];
            v = acc * (1.0f / 32.0f);
        }
        hs[s][j] = v;
        cs[s][j] = 0.0f;
        ews[s][j] = e_w[tid];
    }
    if (tid < 2) ebs[tid] = e_b[tid];
    __syncthreads();

    for (int t = 0; t < 30; ++t) {
        #pragma unroll
        for (int s = 0; s < 2; ++s) {
            const float4* hp = (const float4*)(&hs[s][0]);
            float a0 = 0.f, a1 = 0.f, a2 = 0.f, a3 = 0.f;
            #pragma unroll
            for (int k = 0; k < 32; ++k) {
                float4 h4 = hp[k];
                a0 = __builtin_fmaf(w[4*k+0], h4.x, a0);
                a1 = __builtin_fmaf(w[4*k+1], h4.y, a1);
                a2 = __builtin_fmaf(w[4*k+2], h4.z, a2);
                a3 = __builtin_fmaf(w[4*k+3], h4.w, a3);
            }
            gs[s][tid] = bias + ((a0 + a1) + (a2 + a3));
        }
        __syncthreads();
        if (tid < 256) {
            const int s = tid >> 7, j = tid & 127;
            float4 g4 = *(const float4*)(&gs[s][4 * j]);
            float ig = sigf(g4.x), fg = sigf(g4.y);
            float gg = tanh_fast(g4.z), og = sigf(g4.w);
            float c = fg * cs[s][j] + ig * gg;
            cs[s][j] = c;
            hs[s][j] = og * tanh_fast(c);
        }
        __syncthreads();
        {
            const int wv = tid >> 6, l = tid & 63;
            if (wv < 4) {
                const int s = wv >> 1, o = wv & 1;
                float p = hs[s][l] * ews[o][l] + hs[s][64 + l] * ews[o][64 + l];
                #pragma unroll
                for (int off = 32; off > 0; off >>= 1) p += __shfl_down(p, off);
                if (l == 0) out[((size_t)(blk * 2 + s) * 30 + t) * 2 + o] = p + ebs[o];
            }
        }
    }
}

extern "C" void kernel_launch(void* const* d_in, const int* in_sizes, int n_in,
                              void* d_out, int out_size, void* d_ws, size_t ws_size,
                              hipStream_t stream)
{
    const float* agent_traj = (const float*)d_in[0];
    const float* neigh_traj = (const float*)d_in[1];
    const float* a_wih = (const float*)d_in[2];
    const float* a_whh = (const float*)d_in[3];
    const float* a_bih = (const float*)d_in[4];
    const float* a_bhh = (const float*)d_in[5];
    const float* n_wih = (const float*)d_in[6];
    const float* n_whh = (const float*)d_in[7];
    const float* n_bih = (const float*)d_in[8];
    const float* n_bhh = (const float*)d_in[9];
    const float* d_wih = (const float*)d_in[10];
    const float* d_whh = (const float*)d_in[11];
    const float* d_bih = (const float*)d_in[12];
    const float* d_bhh = (const float*)d_in[13];
    const float* e_w   = (const float*)d_in[14];
    const float* e_b   = (const float*)d_in[15];
    float* out = (float*)d_out;

    float* nh_ws = (float*)d_ws;            // 16384*64 fp32
    float* ah_ws = nh_ws + 16384 * 64;      // 512*64 fp32

    enc2_kernel<<<dim3(264), dim3(256), 0, stream>>>(
        agent_traj, neigh_traj,
        a_wih, a_whh, a_bih, a_bhh,
        n_wih, n_whh, n_bih, n_bhh,
        nh_ws, ah_ws);

    dec_kernel<<<dim3(256), dim3(512), 0, stream>>>(
        ah_ws, nh_ws, d_wih, d_whh, d_bih, d_bhh, e_w, e_b, out);
}

// Round 3
// 326.004 us; speedup vs baseline: 3.8368x; 1.5182x over previous
//
#include <hip/hip_runtime.h>

// ---------------------------------------------------------------------------
// R3: (1) v_rcp instead of IEEE div in sigmoid/tanh (~2x VALU cut);
//     (2) encoder 16 seqs/block -> 1056 blocks, ~4 waves/SIMD (was ~1);
//     (3) decoder rewritten on MFMA (split-bf16, K=128), pred head via LDS;
//     (4) hb row stride padded so col-strided access is 2-way (free) banked.
// ---------------------------------------------------------------------------

typedef __attribute__((ext_vector_type(8))) short bf16x8;
typedef __attribute__((ext_vector_type(4))) float f32x4;
typedef unsigned int uint;
typedef unsigned short ushort_t;

__device__ __forceinline__ float rcp_fast(float x) { return __builtin_amdgcn_rcpf(x); }
__device__ __forceinline__ float sigf(float x) { return rcp_fast(1.0f + __expf(-x)); }
__device__ __forceinline__ float tanh_fast(float x) {
    x = fminf(fmaxf(x, -15.0f), 15.0f);
    float e = __expf(2.0f * x);
    return (e - 1.0f) * rcp_fast(e + 1.0f);
}
__device__ __forceinline__ ushort_t bf_hi(float f) {
    union { float f; uint u; } v; v.f = f;
    return (ushort_t)(v.u >> 16);
}
__device__ __forceinline__ float bf_f(ushort_t h) {
    union { float f; uint u; } v; v.u = ((uint)h) << 16;
    return v.f;
}

// ======================= encoder: H=64, T=50 ==============================
// 16 seqs/block; 4 waves; wave wv owns units 16wv..16wv+15 for all 4 gates.
// hb row: dwords 0..31 = h hi (64 bf16), 32..63 = h lo, pad to 76 dwords.
#define HS 76

__global__ __launch_bounds__(256, 3) void enc3_kernel(
    const float* __restrict__ ax, const float* __restrict__ nx,
    const float* __restrict__ a_wih, const float* __restrict__ a_whh,
    const float* __restrict__ a_bih, const float* __restrict__ a_bhh,
    const float* __restrict__ n_wih, const float* __restrict__ n_whh,
    const float* __restrict__ n_bih, const float* __restrict__ n_bhh,
    float* __restrict__ nh_out, float* __restrict__ ah_out)
{
    const int tid = threadIdx.x, blk = blockIdx.x;
    const bool agent = (blk >= 1024);
    const int seq0 = (agent ? (blk - 1024) : blk) * 16;
    const float* __restrict__ x   = agent ? ax : nx;
    const float* __restrict__ wih = agent ? a_wih : n_wih;
    const float* __restrict__ whh = agent ? a_whh : n_whh;
    const float* __restrict__ bih = agent ? a_bih : n_bih;
    const float* __restrict__ bhh = agent ? a_bhh : n_bhh;
    float* __restrict__ hout = agent ? ah_out : nh_out;

    const int lane = tid & 63, wv = tid >> 6;
    const int col = lane & 15, quad = lane >> 4;

    __shared__ __attribute__((aligned(16))) uint hb[2][16][HS];
    __shared__ float xs[16 * 100];

    // A fragments: Whh rows (A row = g*64 + 16wv + col, k = kt*32 + quad*8 + j)
    bf16x8 Ahi[4][2], Alo[4][2];
    #pragma unroll
    for (int g = 0; g < 4; ++g) {
        #pragma unroll
        for (int kt = 0; kt < 2; ++kt) {
            const float* p = whh + (size_t)(g * 64 + 16 * wv + col) * 64 + kt * 32 + quad * 8;
            float4 v0 = *(const float4*)p;
            float4 v1 = *(const float4*)(p + 4);
            float vv[8] = { v0.x, v0.y, v0.z, v0.w, v1.x, v1.y, v1.z, v1.w };
            bf16x8 h8, l8;
            #pragma unroll
            for (int j = 0; j < 8; ++j) {
                ushort_t hh = bf_hi(vv[j]);
                h8[j] = (short)hh;
                l8[j] = (short)bf_hi(vv[j] - bf_f(hh));
            }
            Ahi[g][kt] = h8;
            Alo[g][kt] = l8;
        }
    }

    // epilogue constants in C/D layout: row = g*64 + 16wv + 4*quad + r
    float bias[4][4], wi0[4][4], wi1[4][4];
    #pragma unroll
    for (int g = 0; g < 4; ++g) {
        #pragma unroll
        for (int r = 0; r < 4; ++r) {
            const int row = g * 64 + 16 * wv + 4 * quad + r;
            bias[g][r] = bih[row] + bhh[row];
            wi0[g][r] = wih[2 * row];
            wi1[g][r] = wih[2 * row + 1];
        }
    }

    {
        const float4* src = (const float4*)(x + (size_t)seq0 * 100);
        for (int i = tid; i < 16 * 25; i += 256) ((float4*)xs)[i] = src[i];
        for (int i = tid; i < 16 * HS; i += 256) (&hb[0][0][0])[i] = 0u;
    }
    __syncthreads();

    float c[4] = {0.f, 0.f, 0.f, 0.f};

    for (int t = 0; t < 50; ++t) {
        const int cur = t & 1, nxt = cur ^ 1;

        // acc = bias + Wih * x_t
        f32x4 acc[4];
        {
            float2 xv = *(const float2*)&xs[col * 100 + 2 * t];
            #pragma unroll
            for (int g = 0; g < 4; ++g) {
                f32x4 a;
                #pragma unroll
                for (int r = 0; r < 4; ++r)
                    a[r] = __builtin_fmaf(wi1[g][r], xv.y,
                           __builtin_fmaf(wi0[g][r], xv.x, bias[g][r]));
                acc[g] = a;
            }
        }

        // Whh @ h via 3-MFMA split
        #pragma unroll
        for (int kt = 0; kt < 2; ++kt) {
            bf16x8 Bhi = *(const bf16x8*)&hb[cur][col][kt * 16 + quad * 4];
            bf16x8 Blo = *(const bf16x8*)&hb[cur][col][32 + kt * 16 + quad * 4];
            #pragma unroll
            for (int g = 0; g < 4; ++g) {
                acc[g] = __builtin_amdgcn_mfma_f32_16x16x32_bf16(Ahi[g][kt], Bhi, acc[g], 0, 0, 0);
                acc[g] = __builtin_amdgcn_mfma_f32_16x16x32_bf16(Ahi[g][kt], Blo, acc[g], 0, 0, 0);
                acc[g] = __builtin_amdgcn_mfma_f32_16x16x32_bf16(Alo[g][kt], Bhi, acc[g], 0, 0, 0);
            }
        }

        // cell update: lane owns seq=col, units 16wv + 4quad + r
        float hv[4];
        #pragma unroll
        for (int r = 0; r < 4; ++r) {
            float ig = sigf(acc[0][r]);
            float fg = sigf(acc[1][r]);
            float gg = tanh_fast(acc[2][r]);
            float og = sigf(acc[3][r]);
            float cc = __builtin_fmaf(fg, c[r], ig * gg);
            c[r] = cc;
            hv[r] = og * tanh_fast(cc);
        }
        {
            ushort_t h0 = bf_hi(hv[0]), h1 = bf_hi(hv[1]);
            ushort_t h2 = bf_hi(hv[2]), h3 = bf_hi(hv[3]);
            uint2 hi2, lo2;
            hi2.x = (uint)h0 | ((uint)h1 << 16);
            hi2.y = (uint)h2 | ((uint)h3 << 16);
            lo2.x = (uint)bf_hi(hv[0] - bf_f(h0)) | ((uint)bf_hi(hv[1] - bf_f(h1)) << 16);
            lo2.y = (uint)bf_hi(hv[2] - bf_f(h2)) | ((uint)bf_hi(hv[3] - bf_f(h3)) << 16);
            const int di = 8 * wv + 2 * quad;
            *(uint2*)&hb[nxt][col][di]      = hi2;
            *(uint2*)&hb[nxt][col][32 + di] = lo2;
        }
        if (t == 49) {
            #pragma unroll
            for (int r = 0; r < 4; ++r)
                hout[(size_t)(seq0 + col) * 64 + 16 * wv + 4 * quad + r] = hv[r];
        }
        __syncthreads();
    }
}

// ======================= decoder: H=128, 30 steps =========================
// 32 blocks x 16 seqs; 8 waves; wave wv owns units 16wv..16wv+15, all gates.
// hb row: dwords 0..63 = h hi (128 bf16), 64..127 = h lo, pad to 148.
#define DS 148

__global__ __launch_bounds__(512, 2) void dec3_kernel(
    const float* __restrict__ ah, const float* __restrict__ nh,
    const float* __restrict__ d_wih, const float* __restrict__ d_whh,
    const float* __restrict__ d_bih, const float* __restrict__ d_bhh,
    const float* __restrict__ e_w, const float* __restrict__ e_b,
    float* __restrict__ out)
{
    const int tid = threadIdx.x, blk = blockIdx.x;
    const int lane = tid & 63, wv = tid >> 6;
    const int col = lane & 15, quad = lane >> 4;

    __shared__ __attribute__((aligned(16))) uint hb[2][16][DS];
    __shared__ float ews[256];

    // A fragments: (d_wih + d_whh) rows, split after fp32 sum.
    bf16x8 Ahi[4][4], Alo[4][4];
    #pragma unroll
    for (int g = 0; g < 4; ++g) {
        #pragma unroll
        for (int kt = 0; kt < 4; ++kt) {
            const size_t off = (size_t)(g * 128 + 16 * wv + col) * 128 + kt * 32 + quad * 8;
            float4 a0 = *(const float4*)(d_wih + off);
            float4 a1 = *(const float4*)(d_wih + off + 4);
            float4 b0 = *(const float4*)(d_whh + off);
            float4 b1 = *(const float4*)(d_whh + off + 4);
            float vv[8] = { a0.x + b0.x, a0.y + b0.y, a0.z + b0.z, a0.w + b0.w,
                            a1.x + b1.x, a1.y + b1.y, a1.z + b1.z, a1.w + b1.w };
            bf16x8 h8, l8;
            #pragma unroll
            for (int j = 0; j < 8; ++j) {
                ushort_t hh = bf_hi(vv[j]);
                h8[j] = (short)hh;
                l8[j] = (short)bf_hi(vv[j] - bf_f(hh));
            }
            Ahi[g][kt] = h8;
            Alo[g][kt] = l8;
        }
    }

    float bias[4][4];
    #pragma unroll
    for (int g = 0; g < 4; ++g)
        #pragma unroll
        for (int r = 0; r < 4; ++r) {
            const int row = g * 128 + 16 * wv + 4 * quad + r;
            bias[g][r] = d_bih[row] + d_bhh[row];
        }

    // h0 = [agent_emb, mean_n(neigh_emb)] -> hb[0] (bf16 hi/lo, via ushort view)
    for (int idx = tid; idx < 16 * 128; idx += 512) {
        const int s = idx >> 7, j = idx & 127;
        const int gseq = blk * 16 + s;
        float v;
        if (j < 64) {
            v = ah[(size_t)gseq * 64 + j];
        } else {
            float acc = 0.0f;
            #pragma unroll 4
            for (int n = 0; n < 32; ++n)
                acc += nh[(size_t)(gseq * 32 + n) * 64 + (j - 64)];
            v = acc * (1.0f / 32.0f);
        }
        ushort_t hh = bf_hi(v);
        ushort_t ll = bf_hi(v - bf_f(hh));
        ushort_t* row = (ushort_t*)&hb[0][s][0];
        row[j] = hh;
        row[128 + j] = ll;   // lo region = dwords 64..127
    }
    if (tid < 256) ews[tid] = e_w[tid];
    __syncthreads();

    float c[4] = {0.f, 0.f, 0.f, 0.f};
    const float eb0 = e_b[0], eb1 = e_b[1];

    for (int t = 0; t < 30; ++t) {
        const int cur = t & 1, nxt = cur ^ 1;

        f32x4 acc[4];
        #pragma unroll
        for (int g = 0; g < 4; ++g) {
            f32x4 a;
            #pragma unroll
            for (int r = 0; r < 4; ++r) a[r] = bias[g][r];
            acc[g] = a;
        }

        #pragma unroll
        for (int kt = 0; kt < 4; ++kt) {
            bf16x8 Bhi = *(const bf16x8*)&hb[cur][col][kt * 16 + quad * 4];
            bf16x8 Blo = *(const bf16x8*)&hb[cur][col][64 + kt * 16 + quad * 4];
            #pragma unroll
            for (int g = 0; g < 4; ++g) {
                acc[g] = __builtin_amdgcn_mfma_f32_16x16x32_bf16(Ahi[g][kt], Bhi, acc[g], 0, 0, 0);
                acc[g] = __builtin_amdgcn_mfma_f32_16x16x32_bf16(Ahi[g][kt], Blo, acc[g], 0, 0, 0);
                acc[g] = __builtin_amdgcn_mfma_f32_16x16x32_bf16(Alo[g][kt], Bhi, acc[g], 0, 0, 0);
            }
        }

        float hv[4];
        #pragma unroll
        for (int r = 0; r < 4; ++r) {
            float ig = sigf(acc[0][r]);
            float fg = sigf(acc[1][r]);
            float gg = tanh_fast(acc[2][r]);
            float og = sigf(acc[3][r]);
            float cc = __builtin_fmaf(fg, c[r], ig * gg);
            c[r] = cc;
            hv[r] = og * tanh_fast(cc);
        }
        {
            ushort_t h0 = bf_hi(hv[0]), h1 = bf_hi(hv[1]);
            ushort_t h2 = bf_hi(hv[2]), h3 = bf_hi(hv[3]);
            uint2 hi2, lo2;
            hi2.x = (uint)h0 | ((uint)h1 << 16);
            hi2.y = (uint)h2 | ((uint)h3 << 16);
            lo2.x = (uint)bf_hi(hv[0] - bf_f(h0)) | ((uint)bf_hi(hv[1] - bf_f(h1)) << 16);
            lo2.y = (uint)bf_hi(hv[2] - bf_f(h2)) | ((uint)bf_hi(hv[3] - bf_f(h3)) << 16);
            const int di = 8 * wv + 2 * quad;
            *(uint2*)&hb[nxt][col][di]      = hi2;
            *(uint2*)&hb[nxt][col][64 + di] = lo2;
        }
        __syncthreads();

        // prediction head: thread -> (seq = tid>>5, o = (tid>>4)&1, part = tid&15)
        {
            const int s = tid >> 5, o = (tid >> 4) & 1, part = tid & 15;
            const ushort_t* row = (const ushort_t*)&hb[nxt][s][0];
            float p = 0.0f;
            #pragma unroll
            for (int j2 = 0; j2 < 8; ++j2) {
                const int j = part * 8 + j2;
                float hvv = bf_f(row[j]) + bf_f(row[128 + j]);
                p = __builtin_fmaf(hvv, ews[o * 128 + j], p);
            }
            #pragma unroll
            for (int off = 8; off > 0; off >>= 1) p += __shfl_down(p, off, 16);
            if (part == 0)
                out[((size_t)(blk * 16 + s) * 30 + t) * 2 + o] = p + (o ? eb1 : eb0);
        }
    }
}

extern "C" void kernel_launch(void* const* d_in, const int* in_sizes, int n_in,
                              void* d_out, int out_size, void* d_ws, size_t ws_size,
                              hipStream_t stream)
{
    const float* agent_traj = (const float*)d_in[0];
    const float* neigh_traj = (const float*)d_in[1];
    const float* a_wih = (const float*)d_in[2];
    const float* a_whh = (const float*)d_in[3];
    const float* a_bih = (const float*)d_in[4];
    const float* a_bhh = (const float*)d_in[5];
    const float* n_wih = (const float*)d_in[6];
    const float* n_whh = (const float*)d_in[7];
    const float* n_bih = (const float*)d_in[8];
    const float* n_bhh = (const float*)d_in[9];
    const float* d_wih = (const float*)d_in[10];
    const float* d_whh = (const float*)d_in[11];
    const float* d_bih = (const float*)d_in[12];
    const float* d_bhh = (const float*)d_in[13];
    const float* e_w   = (const float*)d_in[14];
    const float* e_b   = (const float*)d_in[15];
    float* out = (float*)d_out;

    float* nh_ws = (float*)d_ws;            // 16384*64 fp32
    float* ah_ws = nh_ws + 16384 * 64;      // 512*64 fp32

    enc3_kernel<<<dim3(1024 + 32), dim3(256), 0, stream>>>(
        agent_traj, neigh_traj,
        a_wih, a_whh, a_bih, a_bhh,
        n_wih, n_whh, n_bih, n_bhh,
        nh_ws, ah_ws);

    dec3_kernel<<<dim3(32), dim3(512), 0, stream>>>(
        ah_ws, nh_ws, d_wih, d_whh, d_bih, d_bhh, e_w, e_b, out);
}